// Round 3
// baseline (853.678 us; speedup 1.0000x reference)
//
#include <hip/hip_runtime.h>

#define N_NODES_C   50000
#define N_EDGES_C   1600000
#define FEAT        128
#define NREL        8
#define NBUCKETS    400000
#define NCHUNKS     16
#define CHUNK_NODES 3125
#define CHUNK_KEYS  25000              // buckets per chunk
#define KTOT        1024
#define NKSTEP      32
#define AGG_BLOCKS  6250               // CHUNK_KEYS / 4 waves
#define GEMM_BLOCKS 49                 // ceil(3125/64)
#define WT_BLOCKS   512

// ---------------- workspace layout (bytes) ----------------
// counts8 u32[8][400000] @0 (12.8M) -> dead after scan_c -> X0 @0, X1 @6.4M
// offsets u32[400001]    @12,800,000
// offrel  u8[3,200,000]  @14,400,016
// rank    u16[1.6M]      @17,600,016 -> dead after scatter -> wt(256KB)+csum(1.6M)
// sorted  u32[1.6M]      @20,800,016
// hb      bf16[50000*128]@27,200,016
// bsum/boff              @40,000,016
#define WS2_COUNTS8  0
#define WS2_X0       0
#define WS2_X1       6400000
#define WS2_OFFSETS  12800000
#define WS2_OFFREL   14400016
#define WS2_RANK     17600016
#define WS2_WT       17600016
#define WS2_CSUM     17862160
#define WS2_SORTED   20800016
#define WS2_HB       27200016
#define WS2_BSUM     40000016
#define WS2_BOFF     40002064
#define WS2_NEEDED   40004112

typedef __attribute__((ext_vector_type(8))) short bf16x8;
typedef __attribute__((ext_vector_type(4))) float f32x4;

__device__ __forceinline__ unsigned short f2bf(float f) {
    unsigned u = __float_as_uint(f);
    return (unsigned short)((u + 0x7fffu + ((u >> 16) & 1u)) >> 16);  // RNE
}
__device__ __forceinline__ float bf2f(unsigned short b) {
    return __uint_as_float((unsigned)b << 16);
}

// fused: cast h->bf16 (blocks 0..3124) | zero counts8 (blocks 3125..6249)
__global__ void k_prep(const float* __restrict__ h, unsigned* __restrict__ counts8,
                       unsigned short* __restrict__ hb) {
    int b = blockIdx.x, t = threadIdx.x;
    if (b < 3125) {
        int i = (b * 256 + t) * 8;
        float4 v0 = *(const float4*)&h[i];
        float4 v1 = *(const float4*)&h[i + 4];
        uint4 o;
        o.x = (unsigned)f2bf(v0.x) | ((unsigned)f2bf(v0.y) << 16);
        o.y = (unsigned)f2bf(v0.z) | ((unsigned)f2bf(v0.w) << 16);
        o.z = (unsigned)f2bf(v1.x) | ((unsigned)f2bf(v1.y) << 16);
        o.w = (unsigned)f2bf(v1.z) | ((unsigned)f2bf(v1.w) << 16);
        *(uint4*)&hb[i] = o;
    } else {
        int i = (b - 3125) * 256 + t;           // < 800000
        ((uint4*)counts8)[i] = make_uint4(0u, 0u, 0u, 0u);
    }
}

// XCD-local histogram: atomics stay in the executing XCD's L2 (no cross-XCD
// line ping-pong). rank[e] = (xcd<<8) | rank_within_(key,xcd).
__global__ void k_hist(const int* __restrict__ dst, const int* __restrict__ et,
                       unsigned* __restrict__ counts8, unsigned short* __restrict__ rank) {
    unsigned xcd;
    asm volatile("s_getreg_b32 %0, hwreg(20, 0, 32)" : "=s"(xcd));  // HW_REG_XCC_ID
    xcd &= 7u;
    int e = blockIdx.x * 256 + threadIdx.x;
    if (e < N_EDGES_C) {
        int key = dst[e] * NREL + et[e];
        unsigned rk = atomicAdd(&counts8[xcd * NBUCKETS + key], 1u);
        rank[e] = (unsigned short)((xcd << 8) | rk);
    }
}

__global__ void k_scan_a(const unsigned* __restrict__ counts8, unsigned* __restrict__ bsum) {
    __shared__ unsigned s[1024];
    int t = threadIdx.x;
    int i = blockIdx.x * 1024 + t;
    unsigned v = 0;
    if (i < NBUCKETS) {
#pragma unroll
        for (int x = 0; x < 8; x++) v += counts8[x * NBUCKETS + i];
    }
    s[t] = v;
    __syncthreads();
    for (int o = 512; o > 0; o >>= 1) {
        if (t < o) s[t] += s[t + o];
        __syncthreads();
    }
    if (t == 0) bsum[blockIdx.x] = s[0];
}

__global__ void k_scan_b(const unsigned* __restrict__ bsum, unsigned* __restrict__ boff, int nb) {
    __shared__ unsigned s[512];
    int t = threadIdx.x;
    unsigned v = (t < nb) ? bsum[t] : 0u;
    s[t] = v;
    __syncthreads();
    for (int o = 1; o < 512; o <<= 1) {
        unsigned u = (t >= o) ? s[t - o] : 0u;
        __syncthreads();
        s[t] += u;
        __syncthreads();
    }
    if (t < nb) boff[t] = s[t] - v;
}

// per-key offsets + packed per-xcd u8 prefixes (offrel)
__global__ void k_scan_c(const unsigned* __restrict__ counts8, const unsigned* __restrict__ boff,
                         unsigned* __restrict__ offsets, unsigned long long* __restrict__ offrel) {
    __shared__ unsigned s[1024];
    int t = threadIdx.x;
    int i = blockIdx.x * 1024 + t;
    unsigned c[8];
    unsigned tot = 0;
    if (i < NBUCKETS) {
#pragma unroll
        for (int x = 0; x < 8; x++) { c[x] = counts8[x * NBUCKETS + i]; tot += c[x]; }
    } else {
#pragma unroll
        for (int x = 0; x < 8; x++) c[x] = 0;
    }
    s[t] = tot;
    __syncthreads();
    for (int o = 1; o < 1024; o <<= 1) {
        unsigned u = (t >= o) ? s[t - o] : 0u;
        __syncthreads();
        s[t] += u;
        __syncthreads();
    }
    if (i < NBUCKETS) {
        offsets[i] = boff[blockIdx.x] + s[t] - tot;
        unsigned long long pk = 0;
        unsigned p = 0;
#pragma unroll
        for (int x = 0; x < 8; x++) { pk |= (unsigned long long)(p & 0xffu) << (8 * x); p += c[x]; }
        offrel[i] = pk;
    }
    if (i == NBUCKETS) offsets[i] = N_EDGES_C;
}

// atomic-free scatter: pos = offsets[key] + offrel[key][xcd] + local_rank
__global__ void k_scatter(const int* __restrict__ src, const int* __restrict__ dst,
                          const int* __restrict__ et, const float* __restrict__ norm,
                          const unsigned* __restrict__ offsets,
                          const unsigned char* __restrict__ offrel,
                          const unsigned short* __restrict__ rank,
                          unsigned* __restrict__ sorted) {
    int e = blockIdx.x * 256 + threadIdx.x;
    if (e < N_EDGES_C) {
        int key = dst[e] * NREL + et[e];
        unsigned rv = rank[e];
        unsigned pos = offsets[key] + (unsigned)offrel[key * 8 + (rv >> 8)] + (rv & 0xffu);
        sorted[pos] = ((unsigned)src[e] << 16) | (unsigned)f2bf(norm[e]);
    }
}

// ---- GEMM block body (shared by fused kernel and tail) ----
// out[g,:] = relu( X[row,:] @ Wcat + sum_r csum[g,r]*b[r,:] )
__device__ __forceinline__ void gemm_block(char* Bl, int gb, int cprev,
                                           const unsigned short* __restrict__ Xh,
                                           const unsigned short* __restrict__ wt,
                                           const float* __restrict__ csum,
                                           const float* __restrict__ bias,
                                           float* __restrict__ out) {
    int t = threadIdx.x, w = t >> 6, lane = t & 63;
    int r0 = gb * 64;

    f32x4 acc[8];
#pragma unroll
    for (int i = 0; i < 8; i++) acc[i] = (f32x4){0.f, 0.f, 0.f, 0.f};

    int lrow = r0 + w * 16 + (lane & 15);
    int lrowc = (lrow < CHUNK_NODES) ? lrow : (CHUNK_NODES - 1);
    const unsigned short* Arow = Xh + (size_t)lrowc * KTOT + (lane >> 4) * 8;

    int sn0 = (2 * t) >> 2, skc0 = (2 * t) & 3;
    int sn1 = (2 * t + 1) >> 2, skc1 = (2 * t + 1) & 3;
    int sl0 = ((sn0 * 64 + skc0 * 16) ^ ((sn0 & 7) << 4));
    int sl1 = ((sn1 * 64 + skc1 * 16) ^ ((sn1 & 7) << 4));
    const uint4* g0 = (const uint4*)&wt[sn0 * KTOT + skc0 * 8];
    const uint4* g1 = (const uint4*)&wt[sn1 * KTOT + skc1 * 8];

    *(uint4*)(Bl + sl0) = g0[0];
    *(uint4*)(Bl + sl1) = g1[0];
    __syncthreads();

    int ln = lane & 15;
    int lbase = (lane >> 4) * 16;

    for (int ks = 0; ks < NKSTEP; ks++) {
        int half = (ks & 1) * 8192;
        uint4 p0, p1;
        if (ks + 1 < NKSTEP) {
            p0 = g0[(ks + 1) * 4];
            p1 = g1[(ks + 1) * 4];
        }
        bf16x8 af = *(const bf16x8*)(Arow + ks * 32);
#pragma unroll
        for (int tl = 0; tl < 8; tl++) {
            int n = tl * 16 + ln;
            const bf16x8* bp = (const bf16x8*)(Bl + half + ((n * 64 + lbase) ^ ((n & 7) << 4)));
            acc[tl] = __builtin_amdgcn_mfma_f32_16x16x32_bf16(af, *bp, acc[tl], 0, 0, 0);
        }
        if (ks + 1 < NKSTEP) {
            int half2 = ((ks + 1) & 1) * 8192;
            *(uint4*)(Bl + half2 + sl0) = p0;
            *(uint4*)(Bl + half2 + sl1) = p1;
        }
        __syncthreads();
    }

#pragma unroll
    for (int i = 0; i < 4; i++) {
        int rl = r0 + w * 16 + (lane >> 4) * 4 + i;
        if (rl >= CHUNK_NODES) continue;
        int g = cprev * CHUNK_NODES + rl;
        float4 c0 = *(const float4*)&csum[(size_t)g * 8];
        float4 c1 = *(const float4*)&csum[(size_t)g * 8 + 4];
        float cs[8] = {c0.x, c0.y, c0.z, c0.w, c1.x, c1.y, c1.z, c1.w};
#pragma unroll
        for (int tl = 0; tl < 8; tl++) {
            int col = tl * 16 + ln;
            float v = acc[tl][i];
#pragma unroll
            for (int r = 0; r < 8; r++) v += cs[r] * bias[r * FEAT + col];
            out[(size_t)g * FEAT + col] = fmaxf(v, 0.f);
        }
    }
}

// Heterogeneous dispatch F(c):
//   blocks [0, AGG_BLOCKS)            : agg chunk c -> X[c&1], csum
//   c==0: blocks [AGG, AGG+WT_BLOCKS) : build Wcat^T bf16
//   c>=1: blocks [AGG, AGG+GEMM)      : gemm chunk c-1 from X[(c-1)&1]
__global__ __launch_bounds__(256) void k_fused(const unsigned* __restrict__ sorted,
                                               const unsigned* __restrict__ offsets,
                                               const unsigned short* __restrict__ hb,
                                               unsigned* __restrict__ Xbase,
                                               float* __restrict__ csum,
                                               const float* __restrict__ W,
                                               unsigned short* __restrict__ wt,
                                               const float* __restrict__ bias,
                                               float* __restrict__ out, int chunk) {
    __shared__ char Bl[16384];
    if (blockIdx.x < AGG_BLOCKS) {
        int w = threadIdx.x >> 6, lane = threadIdx.x & 63;
        int lb = blockIdx.x * 4 + w;
        int key = chunk * CHUNK_KEYS + lb;
        unsigned st = offsets[key], en = offsets[key + 1];
        unsigned* X = Xbase + (chunk & 1) * 1600000;

        float a0 = 0.f, a1 = 0.f, cs = 0.f;
        unsigned i = st;
        while (i + 2 <= en) {
            unsigned r0 = sorted[i], r1 = sorted[i + 1];
            float n0 = bf2f((unsigned short)(r0 & 0xffffu));
            float n1 = bf2f((unsigned short)(r1 & 0xffffu));
            unsigned hv0 = *(const unsigned*)&hb[(size_t)(r0 >> 16) * FEAT + lane * 2];
            unsigned hv1 = *(const unsigned*)&hb[(size_t)(r1 >> 16) * FEAT + lane * 2];
            a0 += n0 * __uint_as_float(hv0 << 16) + n1 * __uint_as_float(hv1 << 16);
            a1 += n0 * __uint_as_float(hv0 & 0xffff0000u) + n1 * __uint_as_float(hv1 & 0xffff0000u);
            cs += n0 + n1;
            i += 2;
        }
        if (i < en) {
            unsigned r0 = sorted[i];
            float n0 = bf2f((unsigned short)(r0 & 0xffffu));
            unsigned hv0 = *(const unsigned*)&hb[(size_t)(r0 >> 16) * FEAT + lane * 2];
            a0 += n0 * __uint_as_float(hv0 << 16);
            a1 += n0 * __uint_as_float(hv0 & 0xffff0000u);
            cs += n0;
        }
        X[lb * 64 + lane] = (unsigned)f2bf(a0) | ((unsigned)f2bf(a1) << 16);
        if (lane == 0) csum[key] = cs;
    } else if (chunk == 0) {
        int i = (blockIdx.x - AGG_BLOCKS) * 256 + threadIdx.x;   // < 131072
        int n = i >> 10, rk = i & 1023;
        wt[i] = f2bf(W[rk * FEAT + n]);
    } else {
        const unsigned short* Xh =
            (const unsigned short*)(Xbase + ((chunk - 1) & 1) * 1600000);
        gemm_block(Bl, blockIdx.x - AGG_BLOCKS, chunk - 1, Xh, wt, csum, bias, out);
    }
}

__global__ __launch_bounds__(256) void k_tail(const unsigned* __restrict__ Xbase,
                                              const unsigned short* __restrict__ wt,
                                              const float* __restrict__ csum,
                                              const float* __restrict__ bias,
                                              float* __restrict__ out) {
    __shared__ char Bl[16384];
    const unsigned short* Xh =
        (const unsigned short*)(Xbase + ((NCHUNKS - 1) & 1) * 1600000);
    gemm_block(Bl, blockIdx.x, NCHUNKS - 1, Xh, wt, csum, bias, out);
}

extern "C" void kernel_launch(void* const* d_in, const int* in_sizes, int n_in,
                              void* d_out, int out_size, void* d_ws, size_t ws_size,
                              hipStream_t stream) {
    const float* h    = (const float*)d_in[0];
    const int*   src  = (const int*)d_in[1];
    const int*   dst  = (const int*)d_in[2];
    const int*   et   = (const int*)d_in[3];
    const float* norm = (const float*)d_in[4];
    const float* W    = (const float*)d_in[5];
    const float* b    = (const float*)d_in[6];
    float*       out  = (float*)d_out;

    if (ws_size < (size_t)WS2_NEEDED) return;

    char* ws = (char*)d_ws;
    unsigned*           counts8 = (unsigned*)(ws + WS2_COUNTS8);
    unsigned*           Xbase   = (unsigned*)(ws + WS2_X0);
    unsigned*           offsets = (unsigned*)(ws + WS2_OFFSETS);
    unsigned char*      offrel  = (unsigned char*)(ws + WS2_OFFREL);
    unsigned short*     rank    = (unsigned short*)(ws + WS2_RANK);
    unsigned short*     wt      = (unsigned short*)(ws + WS2_WT);
    float*              csum    = (float*)(ws + WS2_CSUM);
    unsigned*           sorted  = (unsigned*)(ws + WS2_SORTED);
    unsigned short*     hb      = (unsigned short*)(ws + WS2_HB);
    unsigned*           bsum    = (unsigned*)(ws + WS2_BSUM);
    unsigned*           boff    = (unsigned*)(ws + WS2_BOFF);

    int nb = (NBUCKETS + 1023) / 1024;   // 391

    k_prep<<<6250, 256, 0, stream>>>(h, counts8, hb);
    k_hist<<<6250, 256, 0, stream>>>(dst, et, counts8, rank);
    k_scan_a<<<nb, 1024, 0, stream>>>(counts8, bsum);
    k_scan_b<<<1, 512, 0, stream>>>(bsum, boff, nb);
    k_scan_c<<<nb, 1024, 0, stream>>>(counts8, boff, offsets, (unsigned long long*)offrel);
    k_scatter<<<6250, 256, 0, stream>>>(src, dst, et, norm, offsets, offrel, rank, sorted);

    for (int c = 0; c < NCHUNKS; c++) {
        int grid = AGG_BLOCKS + (c == 0 ? WT_BLOCKS : GEMM_BLOCKS);
        k_fused<<<grid, 256, 0, stream>>>(sorted, offsets, hb, Xbase, csum,
                                          W, wt, b, out, c);
    }
    k_tail<<<GEMM_BLOCKS, 256, 0, stream>>>(Xbase, wt, csum, b, out);
}

// Round 4
// 593.919 us; speedup vs baseline: 1.4374x; 1.4374x over previous
//
#include <hip/hip_runtime.h>

#define N_NODES_C   50000
#define N_EDGES_C   1600000
#define FEAT        128
#define NREL        8
#define NBUCKETS    400000
#define KTOT        1024

// ---------------- workspace layout (bytes) ----------------
#define WS3_COUNTS   0          // u32[100000] (u8x4 packed)     400,000
#define WS3_OFFSETS  400000     // u32[400000]                 1,600,000
#define WS3_RANK     2000000    // u8[1.6M]                    1,600,000
#define WS3_BSUM     3600000    // u32[512]                        2,048
#define WS3_BOFF     3602048    // u32[512]                        2,048
#define WS3_SORTED   3604096    // u32[1.6M]                   6,400,000
#define WS3_HB       10004096   // bf16[50000*128]            12,800,000
#define WS3_WT       22804096   // bf16[128][1024]               262,144
#define WS3_NEEDED   23066240

typedef __attribute__((ext_vector_type(8))) short bf16x8;
typedef __attribute__((ext_vector_type(4))) float f32x4;

__device__ __forceinline__ unsigned short f2bf(float f) {
    unsigned u = __float_as_uint(f);
    return (unsigned short)((u + 0x7fffu + ((u >> 16) & 1u)) >> 16);  // RNE
}
__device__ __forceinline__ float bf2f(unsigned short b) {
    return __uint_as_float((unsigned)b << 16);
}
__device__ __forceinline__ float lo16(unsigned u) { return __uint_as_float(u << 16); }
__device__ __forceinline__ float hi16(unsigned u) { return __uint_as_float(u & 0xffff0000u); }

// fused: cast h->bf16 | zero packed counts | build Wcat^T bf16 [n][r*128+k]
__global__ void k_prep(const float* __restrict__ h, const float* __restrict__ W,
                       unsigned* __restrict__ counts, unsigned short* __restrict__ hb,
                       unsigned short* __restrict__ wt) {
    int b = blockIdx.x, t = threadIdx.x;
    if (b < 3125) {                         // h cast: 6.4M elems, 8/thread
        int i = (b * 256 + t) * 8;
        float4 v0 = *(const float4*)&h[i];
        float4 v1 = *(const float4*)&h[i + 4];
        uint4 o;
        o.x = (unsigned)f2bf(v0.x) | ((unsigned)f2bf(v0.y) << 16);
        o.y = (unsigned)f2bf(v0.z) | ((unsigned)f2bf(v0.w) << 16);
        o.z = (unsigned)f2bf(v1.x) | ((unsigned)f2bf(v1.y) << 16);
        o.w = (unsigned)f2bf(v1.z) | ((unsigned)f2bf(v1.w) << 16);
        *(uint4*)&hb[i] = o;
    } else if (b < 3125 + 98) {             // zero 100000 u32 of packed counts
        int i = (b - 3125) * 256 + t;       // uint4 index
        if (i < 25000) ((uint4*)counts)[i] = make_uint4(0u, 0u, 0u, 0u);
    } else {                                // wt[n*1024 + rk] = W[rk*128 + n]
        int i = (b - 3223) * 256 + t;       // 0..131071
        int n = i >> 10, rk = i & 1023;
        wt[i] = f2bf(W[rk * FEAT + n]);
    }
}

// packed u8 histogram: 4 buckets per u32 word (max bucket count << 255).
// rank[e] = pre-increment value of this bucket's byte.
__global__ void k_hist(const int* __restrict__ dst, const int* __restrict__ et,
                       unsigned* __restrict__ counts, unsigned char* __restrict__ rank) {
    int e = blockIdx.x * 256 + threadIdx.x;
    if (e < N_EDGES_C) {
        int key = dst[e] * NREL + et[e];
        int sh = 8 * (key & 3);
        unsigned old = atomicAdd(&counts[key >> 2], 1u << sh);
        rank[e] = (unsigned char)((old >> sh) & 0xffu);
    }
}

__global__ void k_scan_a(const unsigned* __restrict__ counts, unsigned* __restrict__ bsum) {
    __shared__ unsigned s[1024];
    int t = threadIdx.x;
    int i = blockIdx.x * 1024 + t;
    unsigned v = 0;
    if (i < NBUCKETS) v = (counts[i >> 2] >> (8 * (i & 3))) & 0xffu;
    s[t] = v;
    __syncthreads();
    for (int o = 512; o > 0; o >>= 1) {
        if (t < o) s[t] += s[t + o];
        __syncthreads();
    }
    if (t == 0) bsum[blockIdx.x] = s[0];
}

__global__ void k_scan_b(const unsigned* __restrict__ bsum, unsigned* __restrict__ boff, int nb) {
    __shared__ unsigned s[512];
    int t = threadIdx.x;
    unsigned v = (t < nb) ? bsum[t] : 0u;
    s[t] = v;
    __syncthreads();
    for (int o = 1; o < 512; o <<= 1) {
        unsigned u = (t >= o) ? s[t - o] : 0u;
        __syncthreads();
        s[t] += u;
        __syncthreads();
    }
    if (t < nb) boff[t] = s[t] - v;
}

__global__ void k_scan_c(const unsigned* __restrict__ counts, const unsigned* __restrict__ boff,
                         unsigned* __restrict__ offsets) {
    __shared__ unsigned s[1024];
    int t = threadIdx.x;
    int i = blockIdx.x * 1024 + t;
    unsigned v = 0;
    if (i < NBUCKETS) v = (counts[i >> 2] >> (8 * (i & 3))) & 0xffu;
    s[t] = v;
    __syncthreads();
    for (int o = 1; o < 1024; o <<= 1) {
        unsigned u = (t >= o) ? s[t - o] : 0u;
        __syncthreads();
        s[t] += u;
        __syncthreads();
    }
    if (i < NBUCKETS) offsets[i] = boff[blockIdx.x] + s[t] - v;
}

// atomic-free scatter of 4B records: (src<<16) | bf16(norm)
__global__ void k_scatter(const int* __restrict__ src, const int* __restrict__ dst,
                          const int* __restrict__ et, const float* __restrict__ norm,
                          const unsigned* __restrict__ offsets,
                          const unsigned char* __restrict__ rank,
                          unsigned* __restrict__ sorted) {
    int e = blockIdx.x * 256 + threadIdx.x;
    if (e < N_EDGES_C) {
        int key = dst[e] * NREL + et[e];
        unsigned pos = offsets[key] + (unsigned)rank[e];
        sorted[pos] = ((unsigned)src[e] << 16) | (unsigned)f2bf(norm[e]);
    }
}

// Fused aggregate+GEMM, one dispatch, 64 nodes per block.
// Per relation r: 4 waves aggregate 64 (node,r) buckets into a 16KB LDS
// A-tile (4 edges in parallel via lane-groups, shfl_xor combine), barrier,
// then MFMA 16x16x32 with B-fragments straight from L2-resident wt.
// acc accumulates over relations; epilogue adds csum-weighted bias + ReLU.
__global__ __launch_bounds__(256) void k_fused(const unsigned* __restrict__ sorted,
                                               const unsigned* __restrict__ offsets,
                                               const unsigned* __restrict__ counts,
                                               const unsigned short* __restrict__ hb,
                                               const unsigned short* __restrict__ wt,
                                               const float* __restrict__ bias,
                                               float* __restrict__ out) {
    __shared__ char At[16384];          // [64 rows][128 k] bf16, XOR-swizzled
    __shared__ float csLds[64][NREL];   // per (row, rel) norm-sums
    int t = threadIdx.x, w = t >> 6, lane = t & 63;
    int node0 = blockIdx.x * 64;
    int grp  = lane >> 4;               // agg: edge slot | mfma: k-group
    int ln16 = lane & 15;               // agg: feature chunk | mfma: row/col

    f32x4 acc[8];
#pragma unroll
    for (int i = 0; i < 8; i++) acc[i] = (f32x4){0.f, 0.f, 0.f, 0.f};

#pragma unroll 1
    for (int r = 0; r < NREL; r++) {
        // ---- aggregate phase: rows w*16 .. w*16+15 ----
        for (int n = w * 16; n < w * 16 + 16; n++) {
            int node = node0 + n;
            float a[8];
#pragma unroll
            for (int j = 0; j < 8; j++) a[j] = 0.f;
            float cs = 0.f;
            if (node < N_NODES_C) {
                int key = node * NREL + r;
                unsigned st  = offsets[key];
                unsigned cnt = (counts[key >> 2] >> (8 * (key & 3))) & 0xffu;
                unsigned en  = st + cnt;
                for (unsigned base = st; base < en; base += 4) {
                    unsigned ei = base + grp;
                    float nv = 0.f;
                    unsigned row = 0;
                    if (ei < en) {
                        unsigned rec = sorted[ei];
                        nv  = bf2f((unsigned short)(rec & 0xffffu));
                        row = rec >> 16;
                    }
                    uint4 hv = *(const uint4*)&hb[(size_t)row * FEAT + ln16 * 8];
                    a[0] += nv * lo16(hv.x); a[1] += nv * hi16(hv.x);
                    a[2] += nv * lo16(hv.y); a[3] += nv * hi16(hv.y);
                    a[4] += nv * lo16(hv.z); a[5] += nv * hi16(hv.z);
                    a[6] += nv * lo16(hv.w); a[7] += nv * hi16(hv.w);
                    cs += nv;
                }
            }
            // combine the 4 edge-slots (same features live at lane, lane^16, lane^32)
#pragma unroll
            for (int m = 16; m < 64; m <<= 1) {
#pragma unroll
                for (int j = 0; j < 8; j++) a[j] += __shfl_xor(a[j], m);
                cs += __shfl_xor(cs, m);
            }
            if (lane < 16) {
                uint4 o;
                o.x = (unsigned)f2bf(a[0]) | ((unsigned)f2bf(a[1]) << 16);
                o.y = (unsigned)f2bf(a[2]) | ((unsigned)f2bf(a[3]) << 16);
                o.z = (unsigned)f2bf(a[4]) | ((unsigned)f2bf(a[5]) << 16);
                o.w = (unsigned)f2bf(a[6]) | ((unsigned)f2bf(a[7]) << 16);
                *(uint4*)(At + ((n * 256 + ln16 * 16) ^ ((n & 7) << 4))) = o;
            }
            if (lane == 0) csLds[n][r] = cs;
        }
        __syncthreads();

        // ---- MFMA phase: 4 ksteps x 8 col-tiles, B from global wt ----
        const unsigned short* wr = wt + r * FEAT;   // + n*KTOT + klocal
        int arow = w * 16 + ln16;
#pragma unroll
        for (int ks = 0; ks < 4; ks++) {
            bf16x8 af = *(const bf16x8*)(At + ((arow * 256 + ks * 64 + grp * 16) ^ ((arow & 7) << 4)));
#pragma unroll
            for (int tl = 0; tl < 8; tl++) {
                int n = tl * 16 + ln16;
                bf16x8 bf = *(const bf16x8*)(wr + (size_t)n * KTOT + ks * 32 + grp * 8);
                acc[tl] = __builtin_amdgcn_mfma_f32_16x16x32_bf16(af, bf, acc[tl], 0, 0, 0);
            }
        }
        __syncthreads();   // protect At before next relation overwrites
    }

    // ---- epilogue: bias via csum + ReLU. D map: col=lane&15, row=(lane>>4)*4+reg
#pragma unroll
    for (int i = 0; i < 4; i++) {
        int rl = w * 16 + grp * 4 + i;
        int g  = node0 + rl;
        if (g >= N_NODES_C) continue;
        float cs[NREL];
#pragma unroll
        for (int rr = 0; rr < NREL; rr++) cs[rr] = csLds[rl][rr];
#pragma unroll
        for (int tl = 0; tl < 8; tl++) {
            int col = tl * 16 + ln16;
            float v = acc[tl][i];
#pragma unroll
            for (int rr = 0; rr < NREL; rr++) v += cs[rr] * bias[rr * FEAT + col];
            out[(size_t)g * FEAT + col] = fmaxf(v, 0.f);
        }
    }
}

extern "C" void kernel_launch(void* const* d_in, const int* in_sizes, int n_in,
                              void* d_out, int out_size, void* d_ws, size_t ws_size,
                              hipStream_t stream) {
    const float* h    = (const float*)d_in[0];
    const int*   src  = (const int*)d_in[1];
    const int*   dst  = (const int*)d_in[2];
    const int*   et   = (const int*)d_in[3];
    const float* norm = (const float*)d_in[4];
    const float* W    = (const float*)d_in[5];
    const float* b    = (const float*)d_in[6];
    float*       out  = (float*)d_out;

    if (ws_size < (size_t)WS3_NEEDED) return;

    char* ws = (char*)d_ws;
    unsigned*       counts  = (unsigned*)(ws + WS3_COUNTS);
    unsigned*       offsets = (unsigned*)(ws + WS3_OFFSETS);
    unsigned char*  rank    = (unsigned char*)(ws + WS3_RANK);
    unsigned*       bsum    = (unsigned*)(ws + WS3_BSUM);
    unsigned*       boff    = (unsigned*)(ws + WS3_BOFF);
    unsigned*       sorted  = (unsigned*)(ws + WS3_SORTED);
    unsigned short* hb      = (unsigned short*)(ws + WS3_HB);
    unsigned short* wt      = (unsigned short*)(ws + WS3_WT);

    int nb = (NBUCKETS + 1023) / 1024;   // 391

    k_prep<<<3125 + 98 + 512, 256, 0, stream>>>(h, W, counts, hb, wt);
    k_hist<<<6250, 256, 0, stream>>>(dst, et, counts, rank);
    k_scan_a<<<nb, 1024, 0, stream>>>(counts, bsum);
    k_scan_b<<<1, 512, 0, stream>>>(bsum, boff, nb);
    k_scan_c<<<nb, 1024, 0, stream>>>(counts, boff, offsets);
    k_scatter<<<6250, 256, 0, stream>>>(src, dst, et, norm, offsets, rank, sorted);

    k_fused<<<(N_NODES_C + 63) / 64, 256, 0, stream>>>(sorted, offsets, counts,
                                                       hb, wt, b, out);
}

// Round 5
// 321.413 us; speedup vs baseline: 2.6560x; 1.8478x over previous
//
#include <hip/hip_runtime.h>

#define N_NODES_C   50000
#define N_EDGES_C   1600000
#define FEAT        128
#define NREL        8
#define NBUCKETS    400000
#define KTOT        1024
#define TILE        16                 // nodes per block; 50000 = 3125*16 exactly

// ---------------- workspace layout (bytes) ----------------
#define WS3_COUNTS   0          // u32[100000] (u8x4 packed)     400,000
#define WS3_OFFSETS  400000     // u32[400000]                 1,600,000
#define WS3_RANK     2000000    // u8[1.6M]                    1,600,000
#define WS3_BSUM     3600000    // u32[512]                        2,048
#define WS3_BOFF     3602048    // u32[512]                        2,048
#define WS3_SORTED   3604096    // u32[1.6M]                   6,400,000
#define WS3_HB       10004096   // bf16[50000*128]            12,800,000
#define WS3_WT       22804096   // bf16[128][1024]               262,144
#define WS3_NEEDED   23066240

typedef __attribute__((ext_vector_type(8))) short bf16x8;
typedef __attribute__((ext_vector_type(4))) float f32x4;

__device__ __forceinline__ unsigned short f2bf(float f) {
    unsigned u = __float_as_uint(f);
    return (unsigned short)((u + 0x7fffu + ((u >> 16) & 1u)) >> 16);  // RNE
}
__device__ __forceinline__ float bf2f(unsigned short b) {
    return __uint_as_float((unsigned)b << 16);
}
__device__ __forceinline__ float lo16(unsigned u) { return __uint_as_float(u << 16); }
__device__ __forceinline__ float hi16(unsigned u) { return __uint_as_float(u & 0xffff0000u); }

// fused: cast h->bf16 | zero packed counts | build Wcat^T bf16 [n][r*128+k]
__global__ void k_prep(const float* __restrict__ h, const float* __restrict__ W,
                       unsigned* __restrict__ counts, unsigned short* __restrict__ hb,
                       unsigned short* __restrict__ wt) {
    int b = blockIdx.x, t = threadIdx.x;
    if (b < 3125) {                         // h cast: 6.4M elems, 8/thread
        int i = (b * 256 + t) * 8;
        float4 v0 = *(const float4*)&h[i];
        float4 v1 = *(const float4*)&h[i + 4];
        uint4 o;
        o.x = (unsigned)f2bf(v0.x) | ((unsigned)f2bf(v0.y) << 16);
        o.y = (unsigned)f2bf(v0.z) | ((unsigned)f2bf(v0.w) << 16);
        o.z = (unsigned)f2bf(v1.x) | ((unsigned)f2bf(v1.y) << 16);
        o.w = (unsigned)f2bf(v1.z) | ((unsigned)f2bf(v1.w) << 16);
        *(uint4*)&hb[i] = o;
    } else if (b < 3125 + 98) {             // zero 100000 u32 of packed counts
        int i = (b - 3125) * 256 + t;       // uint4 index
        if (i < 25000) ((uint4*)counts)[i] = make_uint4(0u, 0u, 0u, 0u);
    } else {                                // wt[n*1024 + rk] = W[rk*128 + n]
        int i = (b - 3223) * 256 + t;       // 0..131071
        int n = i >> 10, rk = i & 1023;
        wt[i] = f2bf(W[rk * FEAT + n]);
    }
}

// packed u8 histogram: 4 buckets per u32 word (bucket count << 255 w.h.p.)
__global__ void k_hist(const int* __restrict__ dst, const int* __restrict__ et,
                       unsigned* __restrict__ counts, unsigned char* __restrict__ rank) {
    int e = blockIdx.x * 256 + threadIdx.x;
    if (e < N_EDGES_C) {
        int key = dst[e] * NREL + et[e];
        int sh = 8 * (key & 3);
        unsigned old = atomicAdd(&counts[key >> 2], 1u << sh);
        rank[e] = (unsigned char)((old >> sh) & 0xffu);
    }
}

__global__ void k_scan_a(const unsigned* __restrict__ counts, unsigned* __restrict__ bsum) {
    __shared__ unsigned s[1024];
    int t = threadIdx.x;
    int i = blockIdx.x * 1024 + t;
    unsigned v = 0;
    if (i < NBUCKETS) v = (counts[i >> 2] >> (8 * (i & 3))) & 0xffu;
    s[t] = v;
    __syncthreads();
    for (int o = 512; o > 0; o >>= 1) {
        if (t < o) s[t] += s[t + o];
        __syncthreads();
    }
    if (t == 0) bsum[blockIdx.x] = s[0];
}

__global__ void k_scan_b(const unsigned* __restrict__ bsum, unsigned* __restrict__ boff, int nb) {
    __shared__ unsigned s[512];
    int t = threadIdx.x;
    unsigned v = (t < nb) ? bsum[t] : 0u;
    s[t] = v;
    __syncthreads();
    for (int o = 1; o < 512; o <<= 1) {
        unsigned u = (t >= o) ? s[t - o] : 0u;
        __syncthreads();
        s[t] += u;
        __syncthreads();
    }
    if (t < nb) boff[t] = s[t] - v;
}

__global__ void k_scan_c(const unsigned* __restrict__ counts, const unsigned* __restrict__ boff,
                         unsigned* __restrict__ offsets) {
    __shared__ unsigned s[1024];
    int t = threadIdx.x;
    int i = blockIdx.x * 1024 + t;
    unsigned v = 0;
    if (i < NBUCKETS) v = (counts[i >> 2] >> (8 * (i & 3))) & 0xffu;
    s[t] = v;
    __syncthreads();
    for (int o = 1; o < 1024; o <<= 1) {
        unsigned u = (t >= o) ? s[t - o] : 0u;
        __syncthreads();
        s[t] += u;
        __syncthreads();
    }
    if (i < NBUCKETS) offsets[i] = boff[blockIdx.x] + s[t] - v;
}

// atomic-free scatter of 4B records: (src<<16) | bf16(norm)
__global__ void k_scatter(const int* __restrict__ src, const int* __restrict__ dst,
                          const int* __restrict__ et, const float* __restrict__ norm,
                          const unsigned* __restrict__ offsets,
                          const unsigned char* __restrict__ rank,
                          unsigned* __restrict__ sorted) {
    int e = blockIdx.x * 256 + threadIdx.x;
    if (e < N_EDGES_C) {
        int key = dst[e] * NREL + et[e];
        unsigned pos = offsets[key] + (unsigned)rank[e];
        sorted[pos] = ((unsigned)src[e] << 16) | (unsigned)f2bf(norm[e]);
    }
}

// Fused aggregate+GEMM, 16 nodes per block (3125 blocks, no bounds checks).
// Per relation r: each of 4 waves aggregates 4 (node,r) buckets with FULL
// 64-lane row gathers (2 feats/lane), 2-edge-unrolled independent chains,
// into a 4KB swizzled LDS A-tile; barrier; MFMA 16x16x32 with each wave
// covering 2 col-tiles, B-fragments straight from L2-resident wt.
__global__ __launch_bounds__(256) void k_fused(const unsigned* __restrict__ sorted,
                                               const unsigned* __restrict__ offsets,
                                               const unsigned* __restrict__ counts,
                                               const unsigned short* __restrict__ hb,
                                               const unsigned short* __restrict__ wt,
                                               const float* __restrict__ bias,
                                               float* __restrict__ out) {
    __shared__ char At[4096];            // [16 rows][128 k] bf16, XOR-swizzled
    __shared__ float csLds[TILE][NREL];  // per (row, rel) norm-sums
    int t = threadIdx.x, w = t >> 6, lane = t & 63;
    int node0 = blockIdx.x * TILE;
    int grp  = lane >> 4;                // mfma k-group / epilogue row-group
    int ln16 = lane & 15;

    f32x4 acc[2];
    acc[0] = (f32x4){0.f, 0.f, 0.f, 0.f};
    acc[1] = (f32x4){0.f, 0.f, 0.f, 0.f};

#pragma unroll 1
    for (int r = 0; r < NREL; r++) {
        // ---- aggregate: wave w owns rows w*4 .. w*4+3 ----
#pragma unroll 1
        for (int nn = 0; nn < 4; nn++) {
            int n = w * 4 + nn;
            int key = (node0 + n) * NREL + r;
            unsigned st  = offsets[key];
            unsigned cnt = (counts[key >> 2] >> (8 * (key & 3))) & 0xffu;
            unsigned en  = st + cnt;
            float a0 = 0.f, a1 = 0.f, cs = 0.f;
            unsigned i = st;
            while (i + 2 <= en) {        // two independent gather chains
                unsigned r0 = sorted[i], r1 = sorted[i + 1];
                float n0 = bf2f((unsigned short)(r0 & 0xffffu));
                float n1 = bf2f((unsigned short)(r1 & 0xffffu));
                unsigned hv0 = *(const unsigned*)&hb[(size_t)(r0 >> 16) * FEAT + lane * 2];
                unsigned hv1 = *(const unsigned*)&hb[(size_t)(r1 >> 16) * FEAT + lane * 2];
                a0 += n0 * lo16(hv0) + n1 * lo16(hv1);
                a1 += n0 * hi16(hv0) + n1 * hi16(hv1);
                cs += n0 + n1;
                i += 2;
            }
            if (i < en) {
                unsigned r0 = sorted[i];
                float n0 = bf2f((unsigned short)(r0 & 0xffffu));
                unsigned hv0 = *(const unsigned*)&hb[(size_t)(r0 >> 16) * FEAT + lane * 2];
                a0 += n0 * lo16(hv0);
                a1 += n0 * hi16(hv0);
                cs += n0;
            }
            // write row n: lane's 2 features as one u32 (2-way bank alias = free)
            *(unsigned*)(At + ((n * 256 + lane * 4) ^ ((n & 7) << 4))) =
                (unsigned)f2bf(a0) | ((unsigned)f2bf(a1) << 16);
            if (lane == 0) csLds[n][r] = cs;
        }
        __syncthreads();

        // ---- MFMA: 4 ksteps x 2 col-tiles per wave, B from global wt ----
        const unsigned short* wr = wt + r * FEAT;
#pragma unroll
        for (int ks = 0; ks < 4; ks++) {
            bf16x8 af = *(const bf16x8*)(At + ((ln16 * 256 + ks * 64 + grp * 16) ^ ((ln16 & 7) << 4)));
#pragma unroll
            for (int c = 0; c < 2; c++) {
                int ncol = (w * 2 + c) * 16 + ln16;
                bf16x8 bf = *(const bf16x8*)(wr + (size_t)ncol * KTOT + ks * 32 + grp * 8);
                acc[c] = __builtin_amdgcn_mfma_f32_16x16x32_bf16(af, bf, acc[c], 0, 0, 0);
            }
        }
        __syncthreads();   // protect At before next relation overwrites
    }

    // ---- epilogue: bias via csum + ReLU. D map: col=lane&15, row=(lane>>4)*4+reg
#pragma unroll
    for (int i = 0; i < 4; i++) {
        int rl = grp * 4 + i;
        int g  = node0 + rl;
        float cs[NREL];
#pragma unroll
        for (int rr = 0; rr < NREL; rr++) cs[rr] = csLds[rl][rr];
#pragma unroll
        for (int c = 0; c < 2; c++) {
            int col = (w * 2 + c) * 16 + ln16;
            float v = acc[c][i];
#pragma unroll
            for (int rr = 0; rr < NREL; rr++) v += cs[rr] * bias[rr * FEAT + col];
            out[(size_t)g * FEAT + col] = fmaxf(v, 0.f);
        }
    }
}

extern "C" void kernel_launch(void* const* d_in, const int* in_sizes, int n_in,
                              void* d_out, int out_size, void* d_ws, size_t ws_size,
                              hipStream_t stream) {
    const float* h    = (const float*)d_in[0];
    const int*   src  = (const int*)d_in[1];
    const int*   dst  = (const int*)d_in[2];
    const int*   et   = (const int*)d_in[3];
    const float* norm = (const float*)d_in[4];
    const float* W    = (const float*)d_in[5];
    const float* b    = (const float*)d_in[6];
    float*       out  = (float*)d_out;

    if (ws_size < (size_t)WS3_NEEDED) return;

    char* ws = (char*)d_ws;
    unsigned*       counts  = (unsigned*)(ws + WS3_COUNTS);
    unsigned*       offsets = (unsigned*)(ws + WS3_OFFSETS);
    unsigned char*  rank    = (unsigned char*)(ws + WS3_RANK);
    unsigned*       bsum    = (unsigned*)(ws + WS3_BSUM);
    unsigned*       boff    = (unsigned*)(ws + WS3_BOFF);
    unsigned*       sorted  = (unsigned*)(ws + WS3_SORTED);
    unsigned short* hb      = (unsigned short*)(ws + WS3_HB);
    unsigned short* wt      = (unsigned short*)(ws + WS3_WT);

    int nb = (NBUCKETS + 1023) / 1024;   // 391

    k_prep<<<3125 + 98 + 512, 256, 0, stream>>>(h, W, counts, hb, wt);
    k_hist<<<6250, 256, 0, stream>>>(dst, et, counts, rank);
    k_scan_a<<<nb, 1024, 0, stream>>>(counts, bsum);
    k_scan_b<<<1, 512, 0, stream>>>(bsum, boff, nb);
    k_scan_c<<<nb, 1024, 0, stream>>>(counts, boff, offsets);
    k_scatter<<<6250, 256, 0, stream>>>(src, dst, et, norm, offsets, rank, sorted);

    k_fused<<<N_NODES_C / TILE, 256, 0, stream>>>(sorted, offsets, counts,
                                                  hb, wt, b, out);
}